// Round 5
// baseline (3784.213 us; speedup 1.0000x reference)
//
#include <hip/hip_runtime.h>
#include <hip/hip_bf16.h>
#include <math.h>

// Problem dims
#define BATCH 256
#define SEQ   512
#define IN_D  512
#define HID   512
#define FOURH 2048
#define BS_ROWS (BATCH * SEQ)   // 131072

typedef __bf16 bf16x8 __attribute__((ext_vector_type(8)));
typedef float  f32x4  __attribute__((ext_vector_type(4)));
typedef unsigned uint32x4 __attribute__((ext_vector_type(4)));
typedef unsigned long long ull;

__device__ __forceinline__ float sigf(float x)  { return 1.0f / (1.0f + __expf(-x)); }
__device__ __forceinline__ float tanhf_(float x){ return 1.0f - 2.0f / (__expf(2.0f * x) + 1.0f); }

union frag_cvt { ull u[2]; bf16x8 v; };

// ---------------------------------------------------------------------------
// Init: weights -> bf16, fuse biases, zero h/c exchange + flags.
// ---------------------------------------------------------------------------
__global__ __launch_bounds__(256) void init_kernel(
    const float* __restrict__ W_all_w, const float* __restrict__ W_all_b,
    const float* __restrict__ U_all_w, const float* __restrict__ U_all_b,
    const float* __restrict__ W_d_w,
    __bf16* __restrict__ Wb, __bf16* __restrict__ Ub, __bf16* __restrict__ Db,
    float* __restrict__ bias_all,
    unsigned* __restrict__ hz,            // hbuf as u32: 2*256*512/2
    unsigned* __restrict__ cz,
    unsigned* __restrict__ bar)
{
    const int stride = gridDim.x * blockDim.x;
    const int tid0 = blockIdx.x * blockDim.x + threadIdx.x;

    const int nW = FOURH * HID;
    for (int i = tid0; i < nW; i += stride) {
        Wb[i] = (__bf16)W_all_w[i];
        Ub[i] = (__bf16)U_all_w[i];
    }
    const int nD = HID * HID;
    for (int i = tid0; i < nD; i += stride) Db[i] = (__bf16)W_d_w[i];
    for (int i = tid0; i < FOURH; i += stride) bias_all[i] = W_all_b[i] + U_all_b[i];
    const int nH = BATCH * HID;   // per 2 buffers, as u32 = BATCH*HID
    for (int i = tid0; i < nH; i += stride) { hz[i] = 0u; cz[i] = 0u; }
    for (int i = tid0; i < 256 * 32; i += stride) bar[i] = 0u;
}

// ---------------------------------------------------------------------------
// u_proj GEMM: up[B*S, 2048] = x[B*S, 512] @ U_all^T (bf16 out, no bias).
// ---------------------------------------------------------------------------
__global__ __launch_bounds__(256) void uproj_gemm(
    const float* __restrict__ x, const __bf16* __restrict__ Ub,
    __bf16* __restrict__ up)
{
    const unsigned bid = blockIdx.x;
    const unsigned lg = (bid & 7) * 2048u + (bid >> 3);   // XCD-chunked, bijective
    const int cb = lg & 15;
    const int rb = lg >> 4;

    __shared__ __bf16 As[128][64];
    __shared__ __bf16 Bs[128][64];

    const int tid = threadIdx.x;
    const int wave = tid >> 6, lane = tid & 63;
    const int wm = wave >> 1, wn = wave & 1;
    const int lrow = lane & 15, kq = lane >> 4;
    const int sw = (lrow & 7) << 3;

    f32x4 acc[4][4];
    #pragma unroll
    for (int m = 0; m < 4; ++m)
        #pragma unroll
        for (int n = 0; n < 4; ++n) acc[m][n] = (f32x4){0.f, 0.f, 0.f, 0.f};

    const int srow = tid >> 1;
    const int skc  = (tid & 1) * 32;
    const int dsw  = (srow & 7) << 3;

    for (int kk = 0; kk < 512; kk += 64) {
        {
            const float* xs = x + (size_t)(rb * 128 + srow) * 512 + kk + skc;
            #pragma unroll
            for (int j = 0; j < 4; ++j) {
                float4 va = ((const float4*)xs)[2 * j];
                float4 vb = ((const float4*)xs)[2 * j + 1];
                bf16x8 pk;
                pk[0] = (__bf16)va.x; pk[1] = (__bf16)va.y;
                pk[2] = (__bf16)va.z; pk[3] = (__bf16)va.w;
                pk[4] = (__bf16)vb.x; pk[5] = (__bf16)vb.y;
                pk[6] = (__bf16)vb.z; pk[7] = (__bf16)vb.w;
                *(bf16x8*)&As[srow][(skc + j * 8) ^ dsw] = pk;
            }
            const __bf16* bsrc = Ub + (size_t)(cb * 128 + srow) * 512 + kk + skc;
            #pragma unroll
            for (int j = 0; j < 4; ++j)
                *(uint4*)&Bs[srow][(skc + j * 8) ^ dsw] = *(const uint4*)(bsrc + j * 8);
        }
        __syncthreads();

        #pragma unroll
        for (int k2 = 0; k2 < 2; ++k2) {
            const int ke = k2 * 32 + kq * 8;
            bf16x8 af[4], bfr[4];
            #pragma unroll
            for (int m = 0; m < 4; ++m)
                af[m] = *(const bf16x8*)&As[wm * 64 + m * 16 + lrow][ke ^ sw];
            #pragma unroll
            for (int n = 0; n < 4; ++n)
                bfr[n] = *(const bf16x8*)&Bs[wn * 64 + n * 16 + lrow][ke ^ sw];
            #pragma unroll
            for (int m = 0; m < 4; ++m)
                #pragma unroll
                for (int n = 0; n < 4; ++n)
                    acc[m][n] = __builtin_amdgcn_mfma_f32_16x16x32_bf16(af[m], bfr[n], acc[m][n], 0, 0, 0);
        }
        __syncthreads();
    }

    const int colL = lane & 15, r0 = (lane >> 4) * 4;
    const size_t orow0 = (size_t)rb * 128 + wm * 64;
    const int ocol0 = cb * 128 + wn * 64;
    #pragma unroll
    for (int m = 0; m < 4; ++m)
        #pragma unroll
        for (int n = 0; n < 4; ++n)
            #pragma unroll
            for (int i = 0; i < 4; ++i)
                up[(orow0 + m * 16 + r0 + i) * 2048 + ocol0 + n * 16 + colL] = (__bf16)acc[m][n][i];
}

// ---------------------------------------------------------------------------
// Persistent scan. 256 blocks x 512 threads (8 waves), 1 block/CU.
// Block (bg,hcid): batch rows b0=bg*32..+31, hidden cols k0=hcid*16..+15.
// Every wave = (row-half rh, K-quarter kq4); computes ALL 5 units
// (4 gates + W_d) for its 16 rows x 128-K-slice. B weights in 80 VGPRs.
// A-fragments loaded DIRECTLY from global h/c buffers with relaxed
// agent-scope 8B atomic loads (no LDS round trip for A).
// ---------------------------------------------------------------------------
__global__ __launch_bounds__(512) void scan_kernel(
    const __bf16* __restrict__ up,        // [B*S][2048]
    const float* __restrict__ timestamps, // [B][S]
    const __bf16* __restrict__ Wb,        // [2048][512]
    const __bf16* __restrict__ Db,        // [512][512]
    const float* __restrict__ bias_all,   // [2048]
    const float* __restrict__ Wd_b,       // [512]
    __bf16* __restrict__ hbuf,            // [2][256][512]
    __bf16* __restrict__ cbuf,            // [2][256][512]
    unsigned* __restrict__ bar,           // [256][32] flags (128B lines)
    float* __restrict__ out)
{
    const int tid = threadIdx.x;
    const int bid = blockIdx.x;
    const int bg = bid & 7, hcid = bid >> 3;
    const int b0 = bg * 32;
    const int k0 = hcid * 16;
    const int wave = tid >> 6, lane = tid & 63;
    const int lrow = lane & 15, kq = lane >> 4;
    const int rh = wave >> 2, kq4 = wave & 3;
    const int kb = kq4 * 128 + kq * 8;      // this wave-lane's K base

    __shared__ float  exg[16 * 32 * 17];    // [(u*4+kq4)][row][17] ~34 KB
    __shared__ float  exd[4 * 32 * 17];     // [kq4][row][17]       ~8.7 KB
    __shared__ __bf16 Us[2][32][64];        // 8 KB u double buffer
    __shared__ float  Ts[2][32];
    __shared__ float  Cm[512];              // f32 c master
    __shared__ float  BiasW[64];
    __shared__ float  BiasD[16];

    // ---- one-time: B fragments into registers (5 units x 4 kslices) ----
    bf16x8 Bg[4][4], Bd4[4];
    #pragma unroll
    for (int u = 0; u < 4; ++u)
        #pragma unroll
        for (int ks = 0; ks < 4; ++ks)
            Bg[u][ks] = *(const bf16x8*)(Wb + (size_t)(u * 512 + k0 + lrow) * 512 + kb + ks * 32);
    #pragma unroll
    for (int ks = 0; ks < 4; ++ks)
        Bd4[ks] = *(const bf16x8*)(Db + (size_t)(k0 + lrow) * 512 + kb + ks * 32);

    // ---- preamble ----
    if (tid < 64) BiasW[tid] = bias_all[(tid >> 4) * 512 + k0 + (tid & 15)];
    else if (tid < 80) BiasD[tid - 64] = Wd_b[k0 + (tid - 64)];
    Cm[tid] = 0.f;
    if (tid < 256) {
        const int row = tid >> 3, j = tid & 7;
        const __bf16* src = up + ((size_t)(b0 + row) * 512 + 0) * 2048
                               + (j >> 1) * 512 + k0 + (j & 1) * 8;
        *(uint4*)&Us[0][row][(j >> 1) * 16 + (j & 1) * 8] = *(const uint4*)src;
    }
    if (tid < 32) Ts[0][tid] = timestamps[(size_t)(b0 + tid) * 512 + 0];
    __syncthreads();

    const int arow = b0 + rh * 16 + lrow;    // global batch row this lane reads

    #pragma unroll 1
    for (int t = 0; t < SEQ; ++t) {
        const int par = t & 1;

        // ---- S0: wait peers' h/c(t) slices ----
        if (t > 0) {
            if (tid < 32) {
                unsigned* fl = &bar[(bg * 32 + tid) * 32];
                while (__hip_atomic_load(fl, __ATOMIC_RELAXED,
                                         __HIP_MEMORY_SCOPE_AGENT) < (unsigned)t)
                    __builtin_amdgcn_s_sleep(1);
            }
            __syncthreads();
        }

        // ---- A-fragment direct loads (coherent, L1-bypassing) ----
        const __bf16* hs = hbuf + (size_t)par * BATCH * HID;
        const __bf16* cs = cbuf + (size_t)par * BATCH * HID;
        const size_t abase = (size_t)arow * 512 + kb;
        ull ahv[4][2], acv[4][2];
        #pragma unroll
        for (int ks = 0; ks < 4; ++ks) {
            const ull* ph = (const ull*)(hs + abase + ks * 32);
            const ull* pc = (const ull*)(cs + abase + ks * 32);
            ahv[ks][0] = __hip_atomic_load(ph,     __ATOMIC_RELAXED, __HIP_MEMORY_SCOPE_AGENT);
            ahv[ks][1] = __hip_atomic_load(ph + 1, __ATOMIC_RELAXED, __HIP_MEMORY_SCOPE_AGENT);
            acv[ks][0] = __hip_atomic_load(pc,     __ATOMIC_RELAXED, __HIP_MEMORY_SCOPE_AGENT);
            acv[ks][1] = __hip_atomic_load(pc + 1, __ATOMIC_RELAXED, __HIP_MEMORY_SCOPE_AGENT);
        }

        // ---- u/ts(t+1) prefetch (nontemporal; overlaps MFMA) ----
        uint32x4 upf;
        float tpf = 0.f;
        const bool do_pf = (t + 1 < SEQ);
        if (do_pf && tid < 256) {
            const int row = tid >> 3, j = tid & 7;
            upf = __builtin_nontemporal_load(
                (const uint32x4*)(up + ((size_t)(b0 + row) * 512 + (t + 1)) * 2048
                                  + (j >> 1) * 512 + k0 + (j & 1) * 8));
        }
        if (do_pf && tid < 32) tpf = timestamps[(size_t)(b0 + tid) * 512 + (t + 1)];

        // ---- MFMA: 5 units x 4 kslices ----
        f32x4 ag[4], ad;
        #pragma unroll
        for (int u = 0; u < 4; ++u) ag[u] = (f32x4){0.f, 0.f, 0.f, 0.f};
        ad = (f32x4){0.f, 0.f, 0.f, 0.f};
        #pragma unroll
        for (int ks = 0; ks < 4; ++ks) {
            frag_cvt fh; fh.u[0] = ahv[ks][0]; fh.u[1] = ahv[ks][1];
            #pragma unroll
            for (int u = 0; u < 4; ++u)
                ag[u] = __builtin_amdgcn_mfma_f32_16x16x32_bf16(fh.v, Bg[u][ks], ag[u], 0, 0, 0);
            frag_cvt fc; fc.u[0] = acv[ks][0]; fc.u[1] = acv[ks][1];
            ad = __builtin_amdgcn_mfma_f32_16x16x32_bf16(fc.v, Bd4[ks], ad, 0, 0, 0);
        }

        // park prefetched u/ts
        if (do_pf && tid < 256) {
            const int row = tid >> 3, j = tid & 7;
            *(uint32x4*)&Us[par ^ 1][row][(j >> 1) * 16 + (j & 1) * 8] = upf;
        }
        if (do_pf && tid < 32) Ts[par ^ 1][tid] = tpf;

        // ---- epilogue -> padded exchange ----
        {
            const int colL = lane & 15, r0 = (lane >> 4) * 4;
            const int rbase = rh * 16 + r0;
            #pragma unroll
            for (int u = 0; u < 4; ++u)
                #pragma unroll
                for (int i = 0; i < 4; ++i)
                    exg[((u * 4 + kq4) * 32 + rbase + i) * 17 + colL] = ag[u][i];
            #pragma unroll
            for (int i = 0; i < 4; ++i)
                exd[(kq4 * 32 + rbase + i) * 17 + colL] = ad[i];
        }
        __syncthreads();  // S2

        // ---- gate update ----
        float o_def = 0.f;
        {
            const int r = tid >> 4, k = tid & 15;
            float g4[4];
            #pragma unroll
            for (int g = 0; g < 4; ++g)
                g4[g] = BiasW[g * 16 + k] + (float)Us[par][r][g * 16 + k]
                      + exg[((g * 4 + 0) * 32 + r) * 17 + k]
                      + exg[((g * 4 + 1) * 32 + r) * 17 + k]
                      + exg[((g * 4 + 2) * 32 + r) * 17 + k]
                      + exg[((g * 4 + 3) * 32 + r) * 17 + k];
            float dd = BiasD[k]
                     + exd[(0 * 32 + r) * 17 + k] + exd[(1 * 32 + r) * 17 + k]
                     + exd[(2 * 32 + r) * 17 + k] + exd[(3 * 32 + r) * 17 + k];

            const float c_old = Cm[tid];
            const float tt = Ts[par][r];
            const float c_s1  = tanhf_(dd);
            const float c_adj = c_old - c_s1 + c_s1 * tt;
            const float f  = sigf(g4[0]);
            const float ii = sigf(g4[1]);
            const float o  = sigf(g4[2]);
            const float c_tmp = tanhf_(g4[3]);
            const float c_new = f * c_adj + ii * c_tmp;
            const float h_new = o * tanhf_(c_new);
            Cm[tid] = c_new;

            // pair-pack h/c via lane^1 shuffle, 4B agent-scope stores
            const unsigned hb16 = (unsigned)__builtin_bit_cast(unsigned short, (__bf16)h_new);
            const unsigned cb16 = (unsigned)__builtin_bit_cast(unsigned short, (__bf16)c_new);
            const unsigned hn = (unsigned)__shfl_xor((int)hb16, 1);
            const unsigned cn = (unsigned)__shfl_xor((int)cb16, 1);

            if (t == SEQ - 1) {
                __builtin_nontemporal_store(o,
                    &out[((size_t)(b0 + r) * 512 + t) * 512 + k0 + k]);
                const size_t base = (size_t)BATCH * SEQ * HID;
                out[base + (size_t)(b0 + r) * 512 + k0 + k] = h_new;
                out[base + (size_t)BATCH * HID + (size_t)(b0 + r) * 512 + k0 + k] = c_new;
            } else {
                o_def = o;
                if (!(lane & 1)) {
                    const unsigned hp = hb16 | (hn << 16);
                    const unsigned cp = cb16 | (cn << 16);
                    const size_t e = ((size_t)(b0 + r) * 512 + k0 + k) >> 1;
                    unsigned* hd = (unsigned*)(hbuf + (size_t)(par ^ 1) * BATCH * HID);
                    unsigned* cd = (unsigned*)(cbuf + (size_t)(par ^ 1) * BATCH * HID);
                    __hip_atomic_store(hd + e, hp, __ATOMIC_RELAXED, __HIP_MEMORY_SCOPE_AGENT);
                    __hip_atomic_store(cd + e, cp, __ATOMIC_RELAXED, __HIP_MEMORY_SCOPE_AGENT);
                }
            }
        }
        __syncthreads();  // S3: vmcnt(0) -> h/c stores visible at L2

        if (t < SEQ - 1) {
            if (tid == 0)
                __hip_atomic_store(&bar[(bg * 32 + hcid) * 32], (unsigned)(t + 1),
                                   __ATOMIC_RELAXED, __HIP_MEMORY_SCOPE_AGENT);
            {
                const int r = tid >> 4, k = tid & 15;
                __builtin_nontemporal_store(o_def,
                    &out[((size_t)(b0 + r) * 512 + t) * 512 + k0 + k]);
            }
        }
    }
}

// ---------------------------------------------------------------------------
extern "C" void kernel_launch(void* const* d_in, const int* in_sizes, int n_in,
                              void* d_out, int out_size, void* d_ws, size_t ws_size,
                              hipStream_t stream) {
    const float* inputs     = (const float*)d_in[0];
    const float* timestamps = (const float*)d_in[1];
    const float* W_all_w    = (const float*)d_in[2];
    const float* W_all_b    = (const float*)d_in[3];
    const float* U_all_w    = (const float*)d_in[4];
    const float* U_all_b    = (const float*)d_in[5];
    const float* W_d_w      = (const float*)d_in[6];
    const float* W_d_b      = (const float*)d_in[7];
    float* out = (float*)d_out;

    char* ws = (char*)d_ws;
    size_t off = 0;
    auto alloc = [&](size_t bytes) -> void* {
        void* p = ws + off;
        off += (bytes + 255) & ~(size_t)255;
        return p;
    };
    __bf16* Wb       = (__bf16*)alloc((size_t)FOURH * HID * 2);
    __bf16* Ub       = (__bf16*)alloc((size_t)FOURH * HID * 2);
    __bf16* Db       = (__bf16*)alloc((size_t)HID * HID * 2);
    float*  bias_all = (float*) alloc((size_t)FOURH * 4);
    __bf16* hbuf     = (__bf16*)alloc((size_t)2 * BATCH * HID * 2);
    __bf16* cbuf     = (__bf16*)alloc((size_t)2 * BATCH * HID * 2);
    unsigned* bar    = (unsigned*)alloc(256 * 32 * 4);
    __bf16* up       = (__bf16*)alloc((size_t)BS_ROWS * FOURH * 2);  // 512 MB

    hipLaunchKernelGGL(init_kernel, dim3(1024), dim3(256), 0, stream,
                       W_all_w, W_all_b, U_all_w, U_all_b, W_d_w,
                       Wb, Ub, Db, bias_all,
                       (unsigned*)hbuf, (unsigned*)cbuf, bar);

    hipLaunchKernelGGL(uproj_gemm, dim3(16384), dim3(256), 0, stream,
                       inputs, Ub, up);

    void* sargs[] = {
        (void*)&up, (void*)&timestamps, (void*)&Wb, (void*)&Db,
        (void*)&bias_all, (void*)&W_d_b,
        (void*)&hbuf, (void*)&cbuf, (void*)&bar, (void*)&out
    };
    hipLaunchCooperativeKernel((const void*)scan_kernel, dim3(256), dim3(512),
                               sargs, 0, stream);
}

// Round 6
// 2276.754 us; speedup vs baseline: 1.6621x; 1.6621x over previous
//
#include <hip/hip_runtime.h>
#include <hip/hip_bf16.h>
#include <math.h>

// Problem dims
#define BATCH 256
#define SEQ   512
#define IN_D  512
#define HID   512
#define FOURH 2048
#define BS_ROWS (BATCH * SEQ)   // 131072

typedef __bf16 bf16x8 __attribute__((ext_vector_type(8)));
typedef float  f32x4  __attribute__((ext_vector_type(4)));
typedef unsigned uint32x4 __attribute__((ext_vector_type(4)));
typedef unsigned long long ull;

__device__ __forceinline__ float sigf(float x)  { return 1.0f / (1.0f + __expf(-x)); }
__device__ __forceinline__ float tanhf_(float x){ return 1.0f - 2.0f / (__expf(2.0f * x) + 1.0f); }

// ---------------------------------------------------------------------------
// Init: weights -> bf16, fuse biases, zero hc exchange + flags.
// ---------------------------------------------------------------------------
__global__ __launch_bounds__(256) void init_kernel(
    const float* __restrict__ W_all_w, const float* __restrict__ W_all_b,
    const float* __restrict__ U_all_w, const float* __restrict__ U_all_b,
    const float* __restrict__ W_d_w,
    __bf16* __restrict__ Wb, __bf16* __restrict__ Ub, __bf16* __restrict__ Db,
    float* __restrict__ bias_all,
    unsigned* __restrict__ hc,            // [2][256][512] u32 packed h|c<<16
    unsigned* __restrict__ bar)           // [16][2][32]
{
    const int stride = gridDim.x * blockDim.x;
    const int tid0 = blockIdx.x * blockDim.x + threadIdx.x;

    const int nW = FOURH * HID;
    for (int i = tid0; i < nW; i += stride) {
        Wb[i] = (__bf16)W_all_w[i];
        Ub[i] = (__bf16)U_all_w[i];
    }
    const int nD = HID * HID;
    for (int i = tid0; i < nD; i += stride) Db[i] = (__bf16)W_d_w[i];
    for (int i = tid0; i < FOURH; i += stride) bias_all[i] = W_all_b[i] + U_all_b[i];
    for (int i = tid0; i < 2 * BATCH * HID; i += stride) hc[i] = 0u;
    for (int i = tid0; i < 16 * 2 * 32; i += stride) bar[i] = 0u;
}

// ---------------------------------------------------------------------------
// u_proj GEMM: up[B*S, 2048] = x[B*S, 512] @ U_all^T (bf16 out, no bias).
// ---------------------------------------------------------------------------
__global__ __launch_bounds__(256) void uproj_gemm(
    const float* __restrict__ x, const __bf16* __restrict__ Ub,
    __bf16* __restrict__ up)
{
    const unsigned bid = blockIdx.x;
    const unsigned lg = (bid & 7) * 2048u + (bid >> 3);   // XCD-chunked, bijective
    const int cb = lg & 15;
    const int rb = lg >> 4;

    __shared__ __bf16 As[128][64];
    __shared__ __bf16 Bs[128][64];

    const int tid = threadIdx.x;
    const int wave = tid >> 6, lane = tid & 63;
    const int wm = wave >> 1, wn = wave & 1;
    const int lrow = lane & 15, kq = lane >> 4;
    const int sw = (lrow & 7) << 3;

    f32x4 acc[4][4];
    #pragma unroll
    for (int m = 0; m < 4; ++m)
        #pragma unroll
        for (int n = 0; n < 4; ++n) acc[m][n] = (f32x4){0.f, 0.f, 0.f, 0.f};

    const int srow = tid >> 1;
    const int skc  = (tid & 1) * 32;
    const int dsw  = (srow & 7) << 3;

    for (int kk = 0; kk < 512; kk += 64) {
        {
            const float* xs = x + (size_t)(rb * 128 + srow) * 512 + kk + skc;
            #pragma unroll
            for (int j = 0; j < 4; ++j) {
                float4 va = ((const float4*)xs)[2 * j];
                float4 vb = ((const float4*)xs)[2 * j + 1];
                bf16x8 pk;
                pk[0] = (__bf16)va.x; pk[1] = (__bf16)va.y;
                pk[2] = (__bf16)va.z; pk[3] = (__bf16)va.w;
                pk[4] = (__bf16)vb.x; pk[5] = (__bf16)vb.y;
                pk[6] = (__bf16)vb.z; pk[7] = (__bf16)vb.w;
                *(bf16x8*)&As[srow][(skc + j * 8) ^ dsw] = pk;
            }
            const __bf16* bsrc = Ub + (size_t)(cb * 128 + srow) * 512 + kk + skc;
            #pragma unroll
            for (int j = 0; j < 4; ++j)
                *(uint4*)&Bs[srow][(skc + j * 8) ^ dsw] = *(const uint4*)(bsrc + j * 8);
        }
        __syncthreads();

        #pragma unroll
        for (int k2 = 0; k2 < 2; ++k2) {
            const int ke = k2 * 32 + kq * 8;
            bf16x8 af[4], bfr[4];
            #pragma unroll
            for (int m = 0; m < 4; ++m)
                af[m] = *(const bf16x8*)&As[wm * 64 + m * 16 + lrow][ke ^ sw];
            #pragma unroll
            for (int n = 0; n < 4; ++n)
                bfr[n] = *(const bf16x8*)&Bs[wn * 64 + n * 16 + lrow][ke ^ sw];
            #pragma unroll
            for (int m = 0; m < 4; ++m)
                #pragma unroll
                for (int n = 0; n < 4; ++n)
                    acc[m][n] = __builtin_amdgcn_mfma_f32_16x16x32_bf16(af[m], bfr[n], acc[m][n], 0, 0, 0);
        }
        __syncthreads();
    }

    const int colL = lane & 15, r0 = (lane >> 4) * 4;
    const size_t orow0 = (size_t)rb * 128 + wm * 64;
    const int ocol0 = cb * 128 + wn * 64;
    #pragma unroll
    for (int m = 0; m < 4; ++m)
        #pragma unroll
        for (int n = 0; n < 4; ++n)
            #pragma unroll
            for (int i = 0; i < 4; ++i)
                up[(orow0 + m * 16 + r0 + i) * 2048 + ocol0 + n * 16 + colL] = (__bf16)acc[m][n][i];
}

// ---------------------------------------------------------------------------
// Persistent scan. 256 blocks x 512 threads (8 waves), 1 block/CU.
// 16 groups x 16 blocks. Block (grp,blk): batch rows b0=grp*16..+15,
// hidden cols k0=blk*32..+31. Wave (ct,kq4): col-half ct (16 cols),
// K-quarter kq4; computes ALL 5 units (4 gates + W_d). B in 96 VGPRs.
// Exchange: coalesced staged gather of packed h|c u32 (relaxed agent atomics),
// LDS unpack; flags: one 64B-packed line per group per parity.
// ---------------------------------------------------------------------------
__global__ __launch_bounds__(512) void scan_kernel(
    const __bf16* __restrict__ up,        // [B*S][2048]
    const float* __restrict__ timestamps, // [B][S]
    const __bf16* __restrict__ Wb,        // [2048][512]
    const __bf16* __restrict__ Db,        // [512][512]
    const float* __restrict__ bias_all,   // [2048]
    const float* __restrict__ Wd_b,       // [512]
    unsigned* __restrict__ hc,            // [2][256][512] packed h|c
    unsigned* __restrict__ bar,           // [16 grp][2 par][32] (128B lines)
    float* __restrict__ out)
{
    const int tid = threadIdx.x;
    const int bid = blockIdx.x;
    const int grp = bid & 15, blk = bid >> 4;
    const int b0 = grp * 16;
    const int k0 = blk * 32;
    const int wave = tid >> 6, lane = tid & 63;
    const int ct = wave >> 2, kq4 = wave & 3;
    const int lrow = lane & 15, kq = lane >> 4;
    const int swz = (lrow & 7) << 3;
    const int k0w = k0 + ct * 16;
    const int kbase = kq4 * 128 + kq * 8;

    __shared__ __bf16 Ah[16][512];        // 16 KB h tile (swizzled)
    __shared__ __bf16 Ac[16][512];        // 16 KB c tile (swizzled)
    __shared__ float  exg[8][4][16][19];  // ~38 KB gate partials [g*2+ct][kq4][r][k]
    __shared__ float  exd[2][4][16][19];  // ~9.5 KB d partials [ct][kq4][r][k]
    __shared__ __bf16 Us[2][16][128];     // 8 KB u double buffer [r][g*32+kcol]
    __shared__ float  Ts[2][16];
    __shared__ float  Cm[512];            // f32 c master (r*32+kcol)
    __shared__ float  BiasW[128];         // [g*32+kcol]
    __shared__ float  BiasD[32];

    // ---- one-time: B fragments into registers (5 units x 4 kslices) ----
    bf16x8 Bg[4][4], Bd4[4];
    #pragma unroll
    for (int u = 0; u < 4; ++u)
        #pragma unroll
        for (int ks = 0; ks < 4; ++ks)
            Bg[u][ks] = *(const bf16x8*)(Wb + (size_t)(u * 512 + k0w + lrow) * 512 + kbase + ks * 32);
    #pragma unroll
    for (int ks = 0; ks < 4; ++ks)
        Bd4[ks] = *(const bf16x8*)(Db + (size_t)(k0w + lrow) * 512 + kbase + ks * 32);

    // ---- preamble ----
    if (tid < 128) BiasW[tid] = bias_all[(tid >> 5) * 512 + k0 + (tid & 31)];
    else if (tid < 160) BiasD[tid - 128] = Wd_b[k0 + (tid - 128)];
    Cm[tid] = 0.f;
    if (tid < 256) {
        const int row = tid >> 4, j = tid & 15, g = j >> 2, seg = j & 3;
        uint32x4 v = __builtin_nontemporal_load(
            (const uint32x4*)(up + ((size_t)(b0 + row) * 512 + 0) * 2048
                              + g * 512 + k0 + seg * 8));
        *(uint32x4*)&Us[0][row][g * 32 + seg * 8] = v;
    }
    if (tid < 16) Ts[0][tid] = timestamps[(size_t)(b0 + tid) * 512 + 0];
    __syncthreads();

    #pragma unroll 1
    for (int t = 0; t < SEQ; ++t) {
        const int par = t & 1;

        // ---- S0: wait peers (one 64B flag line, 16 lanes coalesced) ----
        if (t > 0) {
            if (tid < 16) {
                unsigned* fl = &bar[(grp * 2 + par) * 32 + tid];
                while (__hip_atomic_load(fl, __ATOMIC_RELAXED,
                                         __HIP_MEMORY_SCOPE_AGENT) < (unsigned)t)
                    __builtin_amdgcn_s_sleep(1);
            }
            __syncthreads();
        }

        // ---- gather hc tile (fully coalesced 8B atomic loads), unpack ----
        {
            const ull* src = (const ull*)(hc + (size_t)par * BATCH * HID) + (size_t)b0 * 256;
            ull v[8];
            #pragma unroll
            for (int i = 0; i < 8; ++i)
                v[i] = __hip_atomic_load(src + i * 512 + tid, __ATOMIC_RELAXED,
                                         __HIP_MEMORY_SCOPE_AGENT);
            #pragma unroll
            for (int i = 0; i < 8; ++i) {
                const int m = i * 512 + tid;
                const int row = m >> 8;              // 256 ull per row
                const int cp = (m & 255) * 2;        // starting col
                const unsigned lo = (unsigned)v[i];
                const unsigned hi = (unsigned)(v[i] >> 32);
                const unsigned h2 = (lo & 0xFFFFu) | (hi << 16);
                const unsigned c2 = (lo >> 16) | (hi & 0xFFFF0000u);
                const int d = cp ^ ((row & 7) << 3);
                *(unsigned*)&Ah[row][d] = h2;
                *(unsigned*)&Ac[row][d] = c2;
            }
        }
        __syncthreads();  // S1

        // ---- u/ts(t+1) prefetch (nontemporal; overlaps MFMA) ----
        uint32x4 upf;
        float tpf = 0.f;
        const bool do_pf = (t + 1 < SEQ);
        if (do_pf && tid < 256) {
            const int row = tid >> 4, j = tid & 15, g = j >> 2, seg = j & 3;
            upf = __builtin_nontemporal_load(
                (const uint32x4*)(up + ((size_t)(b0 + row) * 512 + (t + 1)) * 2048
                                  + g * 512 + k0 + seg * 8));
        }
        if (do_pf && tid < 16) tpf = timestamps[(size_t)(b0 + tid) * 512 + (t + 1)];

        // ---- MFMA: 5 units x 4 kslices, A from LDS ----
        f32x4 ag[4], ad;
        #pragma unroll
        for (int u = 0; u < 4; ++u) ag[u] = (f32x4){0.f, 0.f, 0.f, 0.f};
        ad = (f32x4){0.f, 0.f, 0.f, 0.f};
        #pragma unroll
        for (int ks = 0; ks < 4; ++ks) {
            const int koff = (kbase + ks * 32) ^ swz;
            bf16x8 a_h = *(const bf16x8*)&Ah[lrow][koff];
            #pragma unroll
            for (int u = 0; u < 4; ++u)
                ag[u] = __builtin_amdgcn_mfma_f32_16x16x32_bf16(a_h, Bg[u][ks], ag[u], 0, 0, 0);
            bf16x8 a_c = *(const bf16x8*)&Ac[lrow][koff];
            ad = __builtin_amdgcn_mfma_f32_16x16x32_bf16(a_c, Bd4[ks], ad, 0, 0, 0);
        }

        // park prefetched u/ts
        if (do_pf && tid < 256) {
            const int row = tid >> 4, j = tid & 15, g = j >> 2, seg = j & 3;
            *(uint32x4*)&Us[par ^ 1][row][g * 32 + seg * 8] = upf;
        }
        if (do_pf && tid < 16) Ts[par ^ 1][tid] = tpf;

        // ---- epilogue -> padded exchange (rows = kq*4+i) ----
        {
            const int colL = lane & 15, r0 = kq * 4;
            #pragma unroll
            for (int u = 0; u < 4; ++u)
                #pragma unroll
                for (int i = 0; i < 4; ++i)
                    exg[u * 2 + ct][kq4][r0 + i][colL] = ag[u][i];
            #pragma unroll
            for (int i = 0; i < 4; ++i)
                exd[ct][kq4][r0 + i][colL] = ad[i];
        }
        __syncthreads();  // S2

        // ---- gate update: tid = r*32 + kcol ----
        float o_def = 0.f;
        {
            const int r = tid >> 5, kcol = tid & 31;
            const int ctg = kcol >> 4, k16 = kcol & 15;
            float g4[4];
            #pragma unroll
            for (int g = 0; g < 4; ++g)
                g4[g] = BiasW[g * 32 + kcol] + (float)Us[par][r][g * 32 + kcol]
                      + exg[g * 2 + ctg][0][r][k16] + exg[g * 2 + ctg][1][r][k16]
                      + exg[g * 2 + ctg][2][r][k16] + exg[g * 2 + ctg][3][r][k16];
            float dd = BiasD[kcol]
                     + exd[ctg][0][r][k16] + exd[ctg][1][r][k16]
                     + exd[ctg][2][r][k16] + exd[ctg][3][r][k16];

            const float c_old = Cm[tid];
            const float tt = Ts[par][r];
            const float c_s1  = tanhf_(dd);
            const float c_adj = c_old - c_s1 + c_s1 * tt;
            const float f  = sigf(g4[0]);
            const float ii = sigf(g4[1]);
            const float o  = sigf(g4[2]);
            const float c_tmp = tanhf_(g4[3]);
            const float c_new = f * c_adj + ii * c_tmp;
            const float h_new = o * tanhf_(c_new);
            Cm[tid] = c_new;

            if (t == SEQ - 1) {
                __builtin_nontemporal_store(o,
                    &out[((size_t)(b0 + r) * 512 + t) * 512 + k0 + kcol]);
                const size_t base = (size_t)BATCH * SEQ * HID;
                out[base + (size_t)(b0 + r) * 512 + k0 + kcol] = h_new;
                out[base + (size_t)BATCH * HID + (size_t)(b0 + r) * 512 + k0 + kcol] = c_new;
            } else {
                o_def = o;
                const unsigned hb16 = (unsigned)__builtin_bit_cast(unsigned short, (__bf16)h_new);
                const unsigned cb16 = (unsigned)__builtin_bit_cast(unsigned short, (__bf16)c_new);
                const unsigned pk = hb16 | (cb16 << 16);
                unsigned* dst = hc + (size_t)(par ^ 1) * BATCH * HID
                                   + (size_t)(b0 + r) * 512 + k0 + kcol;
                __hip_atomic_store(dst, pk, __ATOMIC_RELAXED, __HIP_MEMORY_SCOPE_AGENT);
            }
        }
        __syncthreads();  // S3: per-wave vmcnt drain -> hc stores visible

        if (t < SEQ - 1) {
            if (tid == 0)
                __hip_atomic_store(&bar[(grp * 2 + ((t + 1) & 1)) * 32 + blk],
                                   (unsigned)(t + 1),
                                   __ATOMIC_RELAXED, __HIP_MEMORY_SCOPE_AGENT);
            {
                const int r = tid >> 5, kcol = tid & 31;
                __builtin_nontemporal_store(o_def,
                    &out[((size_t)(b0 + r) * 512 + t) * 512 + k0 + kcol]);
            }
        }
    }
}

// ---------------------------------------------------------------------------
extern "C" void kernel_launch(void* const* d_in, const int* in_sizes, int n_in,
                              void* d_out, int out_size, void* d_ws, size_t ws_size,
                              hipStream_t stream) {
    const float* inputs     = (const float*)d_in[0];
    const float* timestamps = (const float*)d_in[1];
    const float* W_all_w    = (const float*)d_in[2];
    const float* W_all_b    = (const float*)d_in[3];
    const float* U_all_w    = (const float*)d_in[4];
    const float* U_all_b    = (const float*)d_in[5];
    const float* W_d_w      = (const float*)d_in[6];
    const float* W_d_b      = (const float*)d_in[7];
    float* out = (float*)d_out;

    char* ws = (char*)d_ws;
    size_t off = 0;
    auto alloc = [&](size_t bytes) -> void* {
        void* p = ws + off;
        off += (bytes + 255) & ~(size_t)255;
        return p;
    };
    __bf16* Wb       = (__bf16*)alloc((size_t)FOURH * HID * 2);
    __bf16* Ub       = (__bf16*)alloc((size_t)FOURH * HID * 2);
    __bf16* Db       = (__bf16*)alloc((size_t)HID * HID * 2);
    float*  bias_all = (float*) alloc((size_t)FOURH * 4);
    unsigned* hcbuf  = (unsigned*)alloc((size_t)2 * BATCH * HID * 4);
    unsigned* bar    = (unsigned*)alloc(16 * 2 * 32 * 4);
    __bf16* up       = (__bf16*)alloc((size_t)BS_ROWS * FOURH * 2);  // 512 MB

    hipLaunchKernelGGL(init_kernel, dim3(1024), dim3(256), 0, stream,
                       W_all_w, W_all_b, U_all_w, U_all_b, W_d_w,
                       Wb, Ub, Db, bias_all, hcbuf, bar);

    hipLaunchKernelGGL(uproj_gemm, dim3(16384), dim3(256), 0, stream,
                       inputs, Ub, up);

    void* sargs[] = {
        (void*)&up, (void*)&timestamps, (void*)&Wb, (void*)&Db,
        (void*)&bias_all, (void*)&W_d_b,
        (void*)&hcbuf, (void*)&bar, (void*)&out
    };
    hipLaunchCooperativeKernel((const void*)scan_kernel, dim3(256), dim3(512),
                               sargs, 0, stream);
}